// Round 1
// baseline (212.357 us; speedup 1.0000x reference)
//
#include <hip/hip_runtime.h>
#include <math.h>

// Problem constants (fixed by reference)
#define GRIDN   14
#define BOXN    2
#define LABELN  20
#define ALL_BOX 10          // 5*BOXN
#define CCH     30          // ALL_BOX + LABELN channels per cell

// R8: small tiles, high occupancy. 64 cells/tile -> 15,360 B LDS/block ->
// 8 blocks/CU (32 waves/CU, 4x R7) with __launch_bounds__(256,8) forcing
// VGPR <= 64. Theory: R7's 2.64 TB/s delivered == 256 CU x ~60 lines x 64B
// / ~900cyc latency (Little's law) -> concurrency-capped, not request-capped.
#define TCELLS  64          // cells per block-tile
#define TF4     480         // float4 per tensor per tile (64*30/4)
#define VTOT    960         // virtual float4 per tile (preds+truths)
#define PBLOCKS 2048        // persistent blocks (8/CU)

typedef float vfloat4 __attribute__((ext_vector_type(4)));

__global__ void yolo_zero_kernel(float* out, int n) {
    int i = blockIdx.x * blockDim.x + threadIdx.x;
    if (i < n) out[i] = 0.0f;
}

// Validated per-cell loss math (absmax 0 in rounds 1-7). Unchanged.
__device__ __forceinline__ float cell_loss(const float* p, const float* t) {
#pragma clang fp contract(off)
    const float CELL = (float)(1.0 / (double)GRIDN);

    const float tx = t[0], ty = t[1], tw = t[2], th_ = t[3], tconf = t[4];
    const bool obj = tconf > 0.0f;

    const float tcx = CELL * tx, tcy = CELL * ty;
    const float thx = tw * 0.5f, thy = th_ * 0.5f;
    const float tltx = tcx - thx, tlty = tcy - thy;
    const float trbx = tcx + thx, trby = tcy + thy;
    const float ta = (trbx - tltx) * (trby - tlty);

    float iou[BOXN], conf[BOXN];
#pragma unroll
    for (int b = 0; b < BOXN; ++b) {
        const float bx = p[b * 5 + 0], by = p[b * 5 + 1];
        const float bw = p[b * 5 + 2], bh = p[b * 5 + 3];
        conf[b] = p[b * 5 + 4];
        const float pcx = CELL * bx, pcy = CELL * by;
        const float phx = bw * 0.5f, phy = bh * 0.5f;
        const float pltx = pcx - phx, plty = pcy - phy;
        const float prbx = pcx + phx, prby = pcy + phy;
        const float ltx = fmaxf(pltx, tltx), lty = fmaxf(plty, tlty);
        const float rbx = fminf(prbx, trbx), rby = fminf(prby, trby);
        const float whx = fmaxf(rbx - ltx, 0.0f);
        const float why = fmaxf(rby - lty, 0.0f);
        const float inter = whx * why;
        const float pa = (prbx - pltx) * (prby - plty);
        iou[b] = inter / (pa + ta - inter);
    }

    const float max_iou = fmaxf(iou[0], iou[1]);
    bool r1;
    if (iou[0] == iou[1]) r1 = !(conf[0] >= conf[1]);
    else                  r1 = !(iou[0] > iou[1]);

    const float rx = r1 ? p[5] : p[0];
    const float ry = r1 ? p[6] : p[1];
    const float rw = r1 ? p[7] : p[2];
    const float rh = r1 ? p[8] : p[3];
    const float rc = r1 ? p[9] : p[4];

    const float dcx = rx - tx;
    const float dcy = ry - ty;
    const float center = dcx * dcx + dcy * dcy;

    const float dsx = sqrtf(rw) - sqrtf(tw);
    const float dsy = sqrtf(rh) - sqrtf(th_);
    const float size = dsx * dsx + dsy * dsy;

    const float dconf = rc - max_iou;
    const float conf_resp = dconf * dconf;

    const float c_other = r1 ? conf[0] : conf[1];
    const float conf_noresp = c_other * c_other;

    const float conf_noobj = conf[0] * conf[0] + conf[1] * conf[1];

    float label = 0.0f;
#pragma unroll
    for (int k = ALL_BOX; k < CCH; ++k) {
        const float d = p[k] - t[k];
        label += d * d;
    }

    const float w  = obj ? 1.0f : 0.0f;
    const float nw = obj ? 0.0f : 1.0f;
    return w * (5.0f * (center + size) + conf_resp + 0.5f * conf_noresp + label)
         + nw * (0.5f * conf_noobj);
}

// R8: same validated pipeline shape as R7 (register prefetch double-buffer,
// lane-contiguous float4 loads, LDS transpose), but 4x the resident waves:
//  - TCELLS 256 -> 64: LDS 61,440 -> 15,360 B/block -> 8 blocks/CU.
//  - __launch_bounds__(256, 8): cap VGPRs at 64 so 8 waves/SIMD fit.
//  - 8 independent barrier domains per CU: load issue is staggered across
//    blocks instead of the R7 convoy (all waves burst 120KB then drain to 0
//    outstanding). Goal: keep per-CU outstanding lines high continuously.
//  - Compute phase: threads 0..63 each do one cell (compute is 7% busy,
//    concentration in one wave is irrelevant).
__global__ __launch_bounds__(256, 8) void yolo_loss_kernel(
    const float* __restrict__ preds,
    const float* __restrict__ truths,
    float* __restrict__ out,
    int ntiles)
{
#pragma clang fp contract(off)
    __shared__ vfloat4 sbuf[VTOT];      // 15,360 B -> 8 blocks/CU

    const int tid = threadIdx.x;

    const vfloat4* pp = (const vfloat4*)preds;
    const vfloat4* tp = (const vfloat4*)truths;

    vfloat4 R[4];
    int tile = blockIdx.x;

    // Prologue: prefetch first tile (virtual idx: [0,480)=preds, rest=truths)
    if (tile < ntiles) {
        const int g = tile * TF4;
#pragma unroll
        for (int i = 0; i < 4; ++i) {
            const int idx = i * 256 + tid;
            if (idx < VTOT)
                R[i] = (idx < TF4) ? pp[g + idx] : tp[g + (idx - TF4)];
        }
    }

    float acc = 0.0f;
    for (; tile < ntiles; tile += PBLOCKS) {
        const int next = tile + PBLOCKS;

        __syncthreads();                     // prev compute done -> LDS reusable
#pragma unroll
        for (int i = 0; i < 4; ++i) {        // ds_write_b128, lane-contiguous
            const int idx = i * 256 + tid;
            if (idx < VTOT) sbuf[idx] = R[i];
        }

        if (next < ntiles) {                 // issue next tile's loads now;
            const int g = next * TF4;        // in flight across compute
#pragma unroll
            for (int i = 0; i < 4; ++i) {
                const int idx = i * 256 + tid;
                if (idx < VTOT)
                    R[i] = (idx < TF4) ? pp[g + idx] : tp[g + (idx - TF4)];
            }
        }
        __syncthreads();                     // tile visible to all waves

        if (tid < TCELLS) {
            const float* sf = (const float*)sbuf;
            acc += cell_loss(sf + tid * CCH, sf + TF4 * 4 + tid * CCH);
        }
    }

    // Only wave 0 holds nonzero acc: wave shuffle -> one atomic per block
    if (tid < 64) {
#pragma unroll
        for (int off = 32; off > 0; off >>= 1) acc += __shfl_down(acc, off, 64);
        if (tid == 0) atomicAdd(out, acc * (1.0f / 4096.0f));
    }
}

extern "C" void kernel_launch(void* const* d_in, const int* in_sizes, int n_in,
                              void* d_out, int out_size, void* d_ws, size_t ws_size,
                              hipStream_t stream) {
    const float* preds  = (const float*)d_in[0];
    const float* truths = (const float*)d_in[1];
    float* out = (float*)d_out;

    const int ncells = in_sizes[0] / CCH;      // 802816
    const int ntiles = ncells / TCELLS;        // 12544 (exact)

    yolo_zero_kernel<<<(out_size + 255) / 256, 256, 0, stream>>>(out, out_size);
    yolo_loss_kernel<<<PBLOCKS, 256, 0, stream>>>(preds, truths, out, ntiles);
}

// Round 3
// 204.173 us; speedup vs baseline: 1.0401x; 1.0401x over previous
//
#include <hip/hip_runtime.h>
#include <math.h>

// Problem constants (fixed by reference)
#define GRIDN   14
#define BOXN    2
#define LABELN  20
#define ALL_BOX 10          // 5*BOXN
#define CCH     30          // ALL_BOX + LABELN channels per cell

// R10: double-buffered LDS with a drain-free barrier placement.
// R7-R8 lesson: "__syncthreads" compiles to "s_waitcnt vmcnt(0) lgkmcnt(0);
// s_barrier". R7 placed it BETWEEN issuing next-tile loads and compute ->
// every prefetch was drained before compute started -> memory duty cycle
// ~40% -> the occupancy-independent ~2.5 TB/s plateau (R8 proved 4x waves
// doesn't move it). R9 (no barriers, wave-private LDS) returned NaN ->
// reverted to the proven cross-wave structure.
// R10 keeps ONE barrier per iteration but moves it so it never drains a
// live prefetch:   write R(t)->buf[p]  (counted vmcnt wait; loads(t) had
// all of compute(t-1) to complete)  ->  barrier (vmcnt already 0: FREE)
// ->  issue loads(t+1)  ->  compute(t) from buf[p].  Loads stay in flight
// across compute + next write. Safety: barrier(k) implies all waves
// finished compute(k-1), so writing buf[p^1] at iter k+1 cannot race.
#define TCELLS  128         // cells per tile (2 buffers fit in 61,440 B LDS)
#define TF4     960         // float4 per tensor per tile (128*30/4)
#define VTOT    1920        // float4 per tile (preds+truths)
#define NREG    8           // ceil(VTOT/256) register-prefetch slots
#define PBLOCKS 512         // persistent blocks (2/CU, LDS-limited)

typedef float vfloat4 __attribute__((ext_vector_type(4)));

__global__ void yolo_zero_kernel(float* out, int n) {
    int i = blockIdx.x * blockDim.x + threadIdx.x;
    if (i < n) out[i] = 0.0f;
}

// Validated per-cell loss math (absmax 0 in rounds 1-8). Unchanged.
__device__ __forceinline__ float cell_loss(const float* p, const float* t) {
#pragma clang fp contract(off)
    const float CELL = (float)(1.0 / (double)GRIDN);

    const float tx = t[0], ty = t[1], tw = t[2], th_ = t[3], tconf = t[4];
    const bool obj = tconf > 0.0f;

    const float tcx = CELL * tx, tcy = CELL * ty;
    const float thx = tw * 0.5f, thy = th_ * 0.5f;
    const float tltx = tcx - thx, tlty = tcy - thy;
    const float trbx = tcx + thx, trby = tcy + thy;
    const float ta = (trbx - tltx) * (trby - tlty);

    float iou[BOXN], conf[BOXN];
#pragma unroll
    for (int b = 0; b < BOXN; ++b) {
        const float bx = p[b * 5 + 0], by = p[b * 5 + 1];
        const float bw = p[b * 5 + 2], bh = p[b * 5 + 3];
        conf[b] = p[b * 5 + 4];
        const float pcx = CELL * bx, pcy = CELL * by;
        const float phx = bw * 0.5f, phy = bh * 0.5f;
        const float pltx = pcx - phx, plty = pcy - phy;
        const float prbx = pcx + phx, prby = pcy + phy;
        const float ltx = fmaxf(pltx, tltx), lty = fmaxf(plty, tlty);
        const float rbx = fminf(prbx, trbx), rby = fminf(prby, trby);
        const float whx = fmaxf(rbx - ltx, 0.0f);
        const float why = fmaxf(rby - lty, 0.0f);
        const float inter = whx * why;
        const float pa = (prbx - pltx) * (prby - plty);
        iou[b] = inter / (pa + ta - inter);
    }

    const float max_iou = fmaxf(iou[0], iou[1]);
    bool r1;
    if (iou[0] == iou[1]) r1 = !(conf[0] >= conf[1]);
    else                  r1 = !(iou[0] > iou[1]);

    const float rx = r1 ? p[5] : p[0];
    const float ry = r1 ? p[6] : p[1];
    const float rw = r1 ? p[7] : p[2];
    const float rh = r1 ? p[8] : p[3];
    const float rc = r1 ? p[9] : p[4];

    const float dcx = rx - tx;
    const float dcy = ry - ty;
    const float center = dcx * dcx + dcy * dcy;

    const float dsx = sqrtf(rw) - sqrtf(tw);
    const float dsy = sqrtf(rh) - sqrtf(th_);
    const float size = dsx * dsx + dsy * dsy;

    const float dconf = rc - max_iou;
    const float conf_resp = dconf * dconf;

    const float c_other = r1 ? conf[0] : conf[1];
    const float conf_noresp = c_other * c_other;

    const float conf_noobj = conf[0] * conf[0] + conf[1] * conf[1];

    float label = 0.0f;
#pragma unroll
    for (int k = ALL_BOX; k < CCH; ++k) {
        const float d = p[k] - t[k];
        label += d * d;
    }

    const float w  = obj ? 1.0f : 0.0f;
    const float nw = obj ? 0.0f : 1.0f;
    return w * (5.0f * (center + size) + conf_resp + 0.5f * conf_noresp + label)
         + nw * (0.5f * conf_noobj);
}

__global__ __launch_bounds__(256, 2) void yolo_loss_kernel(
    const float* __restrict__ preds,
    const float* __restrict__ truths,
    float* __restrict__ out,
    int ntiles)
{
#pragma clang fp contract(off)
    __shared__ vfloat4 sbuf[2 * VTOT];  // 61,440 B -> 2 blocks/CU
    __shared__ float wsum[4];

    const int tid  = threadIdx.x;
    const int wave = tid >> 6;
    const int lane = tid & 63;

    const vfloat4* pp = (const vfloat4*)preds;
    const vfloat4* tp = (const vfloat4*)truths;

    vfloat4 R[NREG];
    int tile = blockIdx.x;

    // Prologue: prefetch first tile (virtual idx: [0,960)=preds, rest=truths)
    if (tile < ntiles) {
        const int g = tile * TF4;
#pragma unroll
        for (int i = 0; i < NREG; ++i) {
            const int idx = i * 256 + tid;
            if (idx < VTOT)
                R[i] = (idx < TF4) ? pp[g + idx] : tp[g + (idx - TF4)];
        }
    }

    float acc = 0.0f;
    int p = 0;
    for (; tile < ntiles; tile += PBLOCKS) {
        vfloat4* buf = sbuf + p * VTOT;

        // Stage R(t) -> buf[p]. The implicit vmcnt wait here consumes
        // loads(t), which were issued one full iteration ago.
#pragma unroll
        for (int i = 0; i < NREG; ++i) {
            const int idx = i * 256 + tid;
            if (idx < VTOT) buf[idx] = R[i];
        }

        // vmcnt is already 0 here -> this barrier's drain is free.
        // Makes buf[p] visible to all waves; guarantees buf[p^1] is no
        // longer being read by any wave (its compute preceded this point).
        __syncthreads();

        const int next = tile + PBLOCKS;
        if (next < ntiles) {                 // issue loads(t+1) now;
            const int g = next * TF4;        // in flight across compute(t)
#pragma unroll
            for (int i = 0; i < NREG; ++i) {
                const int idx = i * 256 + tid;
                if (idx < VTOT)
                    R[i] = (idx < TF4) ? pp[g + idx] : tp[g + (idx - TF4)];
            }
        }

        if (tid < TCELLS) {                  // compute(t): no barrier after
            const float* sf = (const float*)buf;
            acc += cell_loss(sf + tid * CCH, sf + TF4 * 4 + tid * CCH);
        }
        p ^= 1;
    }

    // Per-thread acc -> wave shuffle -> LDS across waves -> one atomic/block
#pragma unroll
    for (int off = 32; off > 0; off >>= 1) acc += __shfl_down(acc, off, 64);
    if (lane == 0) wsum[wave] = acc;
    __syncthreads();
    if (tid == 0) {
        const float s = (wsum[0] + wsum[1]) + (wsum[2] + wsum[3]);
        atomicAdd(out, s * (1.0f / 4096.0f));
    }
}

extern "C" void kernel_launch(void* const* d_in, const int* in_sizes, int n_in,
                              void* d_out, int out_size, void* d_ws, size_t ws_size,
                              hipStream_t stream) {
    const float* preds  = (const float*)d_in[0];
    const float* truths = (const float*)d_in[1];
    float* out = (float*)d_out;

    const int ncells = in_sizes[0] / CCH;      // 802816
    const int ntiles = ncells / TCELLS;        // 6272 (exact)

    yolo_zero_kernel<<<(out_size + 255) / 256, 256, 0, stream>>>(out, out_size);
    yolo_loss_kernel<<<PBLOCKS, 256, 0, stream>>>(preds, truths, out, ntiles);
}